// Round 4
// baseline (145736.670 us; speedup 1.0000x reference)
//
#include <hip/hip_runtime.h>
#include <math.h>

// Problem dims
#define TSTEPS 512
#define BSZ    64
#define INDIM  256
#define HDIM   1024
#define G4     4096
#define N0TOT  5120   // 4096 gate cols + 1024 proj cols
#define K0TOT  1280   // 256 (x) + 1024 (h0)
#define K1TOT  2048   // 1024 (h0') + 1024 (h1)
#define LN_EPS 1e-5f

#define NBLK   256
#define NTHR   1024

// LDS: W1 strip [16 cols][2056] hi then lo (pad 8 kills bank conflicts)
#define LDS_LDK    2056
#define LDS_LO_OFF (16 * LDS_LDK)
#define LDS_W_BYTES (2 * 16 * LDS_LDK * 2)      // 131,584
#define LDS_BYTES  (LDS_W_BYTES + 256)          // + reduce scratch

typedef short          s8v __attribute__((ext_vector_type(8)));
typedef float          f4v __attribute__((ext_vector_type(4)));
typedef unsigned short u16;

__device__ __forceinline__ u16 f2bf(float f) {
    unsigned u = __float_as_uint(f);
    u += 0x7FFFu + ((u >> 16) & 1u);            // RNE
    return (u16)(u >> 16);
}
__device__ __forceinline__ float bf2f(u16 h) {
    return __uint_as_float(((unsigned)h) << 16);
}
__device__ __forceinline__ float sigm(float x) { return 1.f / (1.f + expf(-x)); }

// ---------------- grid barrier (device-scope, sense via monotonic gen) ----
__device__ __forceinline__ void grid_barrier(int* ctr, int* gen, int expect)
{
    __syncthreads();
    if (threadIdx.x == 0) {
        __threadfence();                                    // release our writes
        int v = __hip_atomic_fetch_add(ctr, 1, __ATOMIC_ACQ_REL,
                                       __HIP_MEMORY_SCOPE_AGENT);
        if (v == NBLK - 1) {
            __hip_atomic_store(ctr, 0, __ATOMIC_RELAXED, __HIP_MEMORY_SCOPE_AGENT);
            __hip_atomic_store(gen, expect, __ATOMIC_RELEASE, __HIP_MEMORY_SCOPE_AGENT);
        } else {
            long spins = 0;
            while (__hip_atomic_load(gen, __ATOMIC_ACQUIRE,
                                     __HIP_MEMORY_SCOPE_AGENT) < expect) {
                if (++spins > (1L << 31)) break;            // bounded: no infinite hang
            }
        }
        __threadfence();                                    // acquire others' writes
    }
    __syncthreads();
}

// ---------------- GEMM0 task: one 16x16 tile, K-split 2 ------------------
// task: ks = task&1 (K 640), tile = task>>1: rt = tile&3, ct = tile>>2 (320 col-tiles)
// proj tiles (ct>=256) limited to k<256; empty ranges write zeros.
__device__ __forceinline__ void taskA(int task, int t, int lane,
    const u16* __restrict__ xhi, const u16* __restrict__ xlo,
    const u16* __restrict__ h0hi, const u16* __restrict__ h0lo,
    const u16* __restrict__ W0thi, const u16* __restrict__ W0tlo,
    float* __restrict__ parts0)
{
    const int ks  = task & 1;
    const int tile = task >> 1;
    const int rt  = tile & 3;
    const int ct  = tile >> 2;
    const int row = lane & 15;
    const int kg  = lane >> 4;
    const int m   = rt * 16 + row;
    const int n   = ct * 16 + row;
    int kbeg = ks * 640, kend = kbeg + 640;
    const int klim = (ct >= 256) ? INDIM : K0TOT;
    if (kend > klim) kend = klim;

    f4v acc = {0.f, 0.f, 0.f, 0.f};
    const u16* wh = W0thi + (size_t)n * K0TOT;
    const u16* wl = W0tlo + (size_t)n * K0TOT;

    for (int kc = kbeg; kc < kend; kc += 32) {
        const int kk = kc + kg * 8;
        const u16 *ah, *al;
        if (kc < INDIM) {
            size_t o = ((size_t)(t * BSZ + m)) * INDIM + kk;
            ah = xhi + o; al = xlo + o;
        } else {
            size_t o = (size_t)m * HDIM + (kk - INDIM);
            ah = h0hi + o; al = h0lo + o;
        }
        s8v Ah = *(const s8v*)ah;
        s8v Al = *(const s8v*)al;
        s8v Bh = *(const s8v*)(wh + kk);
        s8v Bl = *(const s8v*)(wl + kk);
        acc = __builtin_amdgcn_mfma_f32_16x16x32_bf16(Ah, Bh, acc, 0, 0, 0);
        acc = __builtin_amdgcn_mfma_f32_16x16x32_bf16(Ah, Bl, acc, 0, 0, 0);
        acc = __builtin_amdgcn_mfma_f32_16x16x32_bf16(Al, Bh, acc, 0, 0, 0);
    }
    float* Cp = parts0 + (size_t)ks * BSZ * N0TOT;
#pragma unroll
    for (int r = 0; r < 4; ++r)
        Cp[(size_t)(rt * 16 + kg * 4 + r) * N0TOT + ct * 16 + row] = acc[r];
}

// ---------------- GEMM1 task: block owns 16 cols (LDS strip) --------------
// wave wv: rt = wv&3 (row tile), ks = wv>>2 (K-split 4, 512 each)
__device__ __forceinline__ void taskC(int blk, int wv, int lane,
    const u16* __restrict__ shW,
    const u16* __restrict__ h0hi, const u16* __restrict__ h0lo,
    const u16* __restrict__ h1hi, const u16* __restrict__ h1lo,
    float* __restrict__ parts1)
{
    const int rt  = wv & 3;
    const int ks  = wv >> 2;
    const int row = lane & 15;
    const int kg  = lane >> 4;
    const int m   = rt * 16 + row;
    const u16* ahB = (ks < 2) ? h0hi : h1hi;
    const u16* alB = (ks < 2) ? h0lo : h1lo;
    const u16* ah0 = ahB + (size_t)m * HDIM + (ks & 1) * 512;
    const u16* al0 = alB + (size_t)m * HDIM + (ks & 1) * 512;
    const u16* sh  = shW + row * LDS_LDK + ks * 512;
    const u16* sl  = shW + LDS_LO_OFF + row * LDS_LDK + ks * 512;

    f4v acc = {0.f, 0.f, 0.f, 0.f};
#pragma unroll 4
    for (int i = 0; i < 16; ++i) {
        const int kloc = i * 32 + kg * 8;
        s8v Ah = *(const s8v*)(ah0 + kloc);
        s8v Al = *(const s8v*)(al0 + kloc);
        s8v Bh = *(const s8v*)(sh + kloc);
        s8v Bl = *(const s8v*)(sl + kloc);
        acc = __builtin_amdgcn_mfma_f32_16x16x32_bf16(Ah, Bh, acc, 0, 0, 0);
        acc = __builtin_amdgcn_mfma_f32_16x16x32_bf16(Ah, Bl, acc, 0, 0, 0);
        acc = __builtin_amdgcn_mfma_f32_16x16x32_bf16(Al, Bh, acc, 0, 0, 0);
    }
    float* Cp = parts1 + (size_t)ks * BSZ * G4;
#pragma unroll
    for (int r = 0; r < 4; ++r)
        Cp[(size_t)(rt * 16 + kg * 4 + r) * G4 + blk * 16 + row] = acc[r];
}

// ---------------- block-wide sum of (s, q) over 1024 threads --------------
__device__ __forceinline__ float2 blk_sum2(float s, float q, float* red, int tid)
{
#pragma unroll
    for (int off = 32; off; off >>= 1) {
        s += __shfl_down(s, off);
        q += __shfl_down(q, off);
    }
    if ((tid & 63) == 0) { red[(tid >> 6) * 2] = s; red[(tid >> 6) * 2 + 1] = q; }
    __syncthreads();
    float ts = 0.f, tq = 0.f;
#pragma unroll
    for (int i = 0; i < 16; ++i) { ts += red[2 * i]; tq += red[2 * i + 1]; }
    __syncthreads();
    return make_float2(ts, tq);
}

__device__ __forceinline__ float lnorm(float v, float2 sq, float g, float b)
{
    float mean = sq.x * (1.f / 1024.f);
    float var  = sq.y * (1.f / 1024.f) - mean * mean;
    return (v - mean) * rsqrtf(var + LN_EPS) * g + b;
}

// =====================================================================
__global__ __launch_bounds__(NTHR, 4) void persistent(
    const u16* __restrict__ xhi,  const u16* __restrict__ xlo,
    const u16* __restrict__ W0thi, const u16* __restrict__ W0tlo,
    const u16* __restrict__ W1ghi, const u16* __restrict__ W1glo,
    const float* __restrict__ b0, const float* __restrict__ b1,
    const float* __restrict__ lncg, const float* __restrict__ lncb,
    const float* __restrict__ lnhg, const float* __restrict__ lnhb,
    const float* __restrict__ lnog, const float* __restrict__ lnob,
    float* __restrict__ parts0, float* __restrict__ parts1,
    float* __restrict__ h0f, float* __restrict__ c0f,
    float* __restrict__ h1f, float* __restrict__ c1f,
    u16* __restrict__ h0hi, u16* __restrict__ h0lo,
    u16* __restrict__ h1hi, u16* __restrict__ h1lo,
    float* __restrict__ out, int* bar)
{
    extern __shared__ char smem[];
    u16*   shW = (u16*)smem;
    float* red = (float*)(smem + LDS_W_BYTES);

    const int blk  = blockIdx.x;
    const int tid  = threadIdx.x;
    const int wv   = tid >> 6;
    const int lane = tid & 63;
    int* ctr = bar;
    int* gen = bar + 32;          // separate cacheline
    int nbar = 0;

    // ---- prologue: LDS W1 strip (block owns cols blk*16..+16) ----
    {
        const size_t gcol = (size_t)(blk * 16 + wv) * K1TOT;
        for (int j = lane * 8; j < K1TOT; j += 512) {
            *(s8v*)(shW + wv * LDS_LDK + j)              = *(const s8v*)(W1ghi + gcol + j);
            *(s8v*)(shW + LDS_LO_OFF + wv * LDS_LDK + j) = *(const s8v*)(W1glo + gcol + j);
        }
    }
    // ---- zero states (262144 threads cover 4x65536 fp32 + 4x65536 bf16) ----
    {
        int gid = blk * NTHR + tid;
        int a = gid >> 16, i = gid & 65535;
        float* dst = (a == 0) ? h0f : (a == 1) ? c0f : (a == 2) ? h1f : c1f;
        dst[i] = 0.f;
        if (a == 0) { h0hi[i] = 0; h0lo[i] = 0; h1hi[i] = 0; h1lo[i] = 0; }
    }
    grid_barrier(ctr, gen, ++nbar);

    // ---- A(0) ----
    if (blk >= 64) {
        int wid = (blk - 64) * 16 + wv;
        if (wid < 2560)
            taskA(wid, 0, lane, xhi, xlo, h0hi, h0lo, W0thi, W0tlo, parts0);
    }
    grid_barrier(ctr, gen, ++nbar);

    for (int t = 0; t < TSTEPS; ++t) {
        // ---- phase B: cell0 (blocks 0..63, row b = blk) ----
        if (blk < 64) {
            const int b = blk, n = tid;
            const float* P0 = parts0 + (size_t)b * N0TOT;
            const float* P1 = parts0 + (size_t)(BSZ + b) * N0TOT;
            float gi = P0[n]        + P1[n]        + b0[n];
            float gf = P0[1024 + n] + P1[1024 + n] + b0[1024 + n];
            float gg = P0[2048 + n] + P1[2048 + n] + b0[2048 + n];
            float go = P0[3072 + n] + P1[3072 + n] + b0[3072 + n];
            float xp = P0[4096 + n] + P1[4096 + n];
            float cv = sigm(gf) * c0f[b * HDIM + n] + expf(gi) * tanhf(gg);
            float2 r = blk_sum2(cv, cv * cv, red, tid);
            float cl = lnorm(cv, r, lncg[n], lncb[n]);
            c0f[b * HDIM + n] = cl;
            float hv = sigm(go) * tanhf(cl);
            r = blk_sum2(hv, hv * hv, red, tid);
            float hl = lnorm(hv, r, lnhg[n], lnhb[n]) + xp;
            r = blk_sum2(hl, hl * hl, red, tid);
            float hn = lnorm(hl, r, lnog[n], lnob[n]);
            h0f[b * HDIM + n] = hn;
            u16 hi = f2bf(hn);
            h0hi[b * HDIM + n] = hi;
            h0lo[b * HDIM + n] = f2bf(hn - bf2f(hi));
        }
        grid_barrier(ctr, gen, ++nbar);

        // ---- phase C: GEMM1 (all blocks, own 16-col LDS strip) ----
        taskC(blk, wv, lane, shW, h0hi, h0lo, h1hi, h1lo, parts1);
        grid_barrier(ctr, gen, ++nbar);

        // ---- phase D (cell1, blocks 0..63) || A(t+1) (blocks 64..255) ----
        if (blk < 64) {
            const int b = blk, n = tid;
            const float* P0 = parts1 + (size_t)b * G4;
            const float* P1 = parts1 + (size_t)(64 + b) * G4;
            const float* P2 = parts1 + (size_t)(128 + b) * G4;
            const float* P3 = parts1 + (size_t)(192 + b) * G4;
            float gi = P0[n] + P1[n] + P2[n] + P3[n] + b1[n];
            float gf = P0[1024 + n] + P1[1024 + n] + P2[1024 + n] + P3[1024 + n] + b1[1024 + n];
            float gg = P0[2048 + n] + P1[2048 + n] + P2[2048 + n] + P3[2048 + n] + b1[2048 + n];
            float go = P0[3072 + n] + P1[3072 + n] + P2[3072 + n] + P3[3072 + n] + b1[3072 + n];
            float cv = sigm(gf) * c1f[b * HDIM + n] + expf(gi) * tanhf(gg);
            float2 r = blk_sum2(cv, cv * cv, red, tid);
            float cl = lnorm(cv, r, lncg[HDIM + n], lncb[HDIM + n]);
            c1f[b * HDIM + n] = cl;
            float hv = sigm(go) * tanhf(cl);
            r = blk_sum2(hv, hv * hv, red, tid);
            float hl = lnorm(hv, r, lnhg[HDIM + n], lnhb[HDIM + n]) + h0f[b * HDIM + n];
            r = blk_sum2(hl, hl * hl, red, tid);
            float hn = lnorm(hl, r, lnog[HDIM + n], lnob[HDIM + n]);
            h1f[b * HDIM + n] = hn;
            u16 hi = f2bf(hn);
            h1hi[b * HDIM + n] = hi;
            h1lo[b * HDIM + n] = f2bf(hn - bf2f(hi));
            out[(size_t)t * BSZ * HDIM + b * HDIM + n] = hn;
        } else if (t + 1 < TSTEPS) {
            int wid = (blk - 64) * 16 + wv;
            if (wid < 2560)
                taskA(wid, t + 1, lane, xhi, xlo, h0hi, h0lo, W0thi, W0tlo, parts0);
        }
        grid_barrier(ctr, gen, ++nbar);
    }

    // ---- final states: output order h0,h1 then c0,c1 ----
    {
        int gid = blk * NTHR + tid;
        int a = gid >> 16, i = gid & 65535;
        const float* src = (a == 0) ? h0f : (a == 1) ? h1f : (a == 2) ? c0f : c1f;
        out[(size_t)TSTEPS * BSZ * HDIM + (size_t)a * 65536 + i] = src[i];
    }
}

// =====================================================================
// prep kernels
// =====================================================================
__global__ __launch_bounds__(256) void transpose_split(
    const float* __restrict__ src, int N,
    u16* __restrict__ dsthi, u16* __restrict__ dstlo,
    int ldd, int noff, int koff)
{
    __shared__ float tile[32][33];
    const int n0 = blockIdx.x * 32, k0 = blockIdx.y * 32;
    const int tx = threadIdx.x & 31, ty = threadIdx.x >> 5;
#pragma unroll
    for (int i = 0; i < 4; ++i)
        tile[ty + i * 8][tx] = src[(size_t)(k0 + ty + i * 8) * N + n0 + tx];
    __syncthreads();
#pragma unroll
    for (int i = 0; i < 4; ++i) {
        float v = tile[tx][ty + i * 8];
        u16 hi = f2bf(v);
        u16 lo = f2bf(v - bf2f(hi));
        size_t idx = (size_t)(n0 + ty + i * 8 + noff) * ldd + k0 + koff + tx;
        dsthi[idx] = hi;
        dstlo[idx] = lo;
    }
}

__global__ void conv_split(const float* __restrict__ src,
                           u16* __restrict__ hi, u16* __restrict__ lo, int n4)
{
    int i = blockIdx.x * 256 + threadIdx.x;
    if (i < n4) {
        float4 v = ((const float4*)src)[i];
        ushort4 h, l;
        h.x = f2bf(v.x); l.x = f2bf(v.x - bf2f(h.x));
        h.y = f2bf(v.y); l.y = f2bf(v.y - bf2f(h.y));
        h.z = f2bf(v.z); l.z = f2bf(v.z - bf2f(h.z));
        h.w = f2bf(v.w); l.w = f2bf(v.w - bf2f(h.w));
        ((ushort4*)hi)[i] = h;
        ((ushort4*)lo)[i] = l;
    }
}

// =====================================================================
extern "C" void kernel_launch(void* const* d_in, const int* in_sizes, int n_in,
                              void* d_out, int out_size, void* d_ws, size_t ws_size,
                              hipStream_t stream)
{
    const float* x     = (const float*)d_in[0];
    const float* Wproj = (const float*)d_in[1];
    const float* Wx0   = (const float*)d_in[2];
    const float* Wh0   = (const float*)d_in[3];
    const float* b0    = (const float*)d_in[4];
    const float* Wx1   = (const float*)d_in[5];
    const float* Wh1   = (const float*)d_in[6];
    const float* b1    = (const float*)d_in[7];
    const float* lnc_g = (const float*)d_in[8];
    const float* lnc_b = (const float*)d_in[9];
    const float* lnh_g = (const float*)d_in[10];
    const float* lnh_b = (const float*)d_in[11];
    const float* lno_g = (const float*)d_in[12];
    const float* lno_b = (const float*)d_in[13];
    float* out = (float*)d_out;

    // ---- ws layout (bytes) ----
    char* base = (char*)d_ws;
    size_t o = 0;
    u16* x_hi  = (u16*)(base + o); o += (size_t)TSTEPS * BSZ * INDIM * 2;   // 16,777,216
    u16* x_lo  = (u16*)(base + o); o += (size_t)TSTEPS * BSZ * INDIM * 2;
    u16* W0thi = (u16*)(base + o); o += (size_t)N0TOT * K0TOT * 2;          // 13,107,200
    u16* W0tlo = (u16*)(base + o); o += (size_t)N0TOT * K0TOT * 2;
    u16* W1ghi = (u16*)(base + o); o += (size_t)G4 * K1TOT * 2;             // 16,777,216
    u16* W1glo = (u16*)(base + o); o += (size_t)G4 * K1TOT * 2;
    float* parts0 = (float*)(base + o); o += (size_t)2 * BSZ * N0TOT * 4;   //  2,621,440
    float* parts1 = (float*)(base + o); o += (size_t)4 * BSZ * G4 * 4;      //  4,194,304
    float* h0f = (float*)(base + o); o += 65536 * 4;
    float* c0f = (float*)(base + o); o += 65536 * 4;
    float* h1f = (float*)(base + o); o += 65536 * 4;
    float* c1f = (float*)(base + o); o += 65536 * 4;
    u16* h0hi = (u16*)(base + o); o += 65536 * 2;
    u16* h0lo = (u16*)(base + o); o += 65536 * 2;
    u16* h1hi = (u16*)(base + o); o += 65536 * 2;
    u16* h1lo = (u16*)(base + o); o += 65536 * 2;
    int* bar  = (int*)(base + o); o += 256;
    if (ws_size < o) return;   // workspace too small: fail loudly (no corruption)

    // ---- prep ----
    conv_split<<<dim3(8192), 256, 0, stream>>>(x, x_hi, x_lo, 2097152);
    hipMemsetAsync(W0thi, 0, (size_t)2 * N0TOT * K0TOT * 2, stream);  // hi+lo contiguous
    transpose_split<<<dim3(128, 8),  256, 0, stream>>>(Wx0,   G4,   W0thi, W0tlo, K0TOT, 0,    0);
    transpose_split<<<dim3(128, 32), 256, 0, stream>>>(Wh0,   G4,   W0thi, W0tlo, K0TOT, 0,    256);
    transpose_split<<<dim3(32, 8),   256, 0, stream>>>(Wproj, HDIM, W0thi, W0tlo, K0TOT, 4096, 0);
    transpose_split<<<dim3(128, 32), 256, 0, stream>>>(Wx1,   G4,   W1ghi, W1glo, K1TOT, 0,    0);
    transpose_split<<<dim3(128, 32), 256, 0, stream>>>(Wh1,   G4,   W1ghi, W1glo, K1TOT, 0,    1024);
    hipMemsetAsync(bar, 0, 256, stream);

    // ---- the whole recurrence: one persistent kernel ----
    persistent<<<dim3(NBLK), dim3(NTHR), LDS_BYTES, stream>>>(
        x_hi, x_lo, W0thi, W0tlo, W1ghi, W1glo, b0, b1,
        lnc_g, lnc_b, lnh_g, lnh_b, lno_g, lno_b,
        parts0, parts1, h0f, c0f, h1f, c1f,
        h0hi, h0lo, h1hi, h1lo, out, bar);
}

// Round 5
// 54219.556 us; speedup vs baseline: 2.6879x; 2.6879x over previous
//
#include <hip/hip_runtime.h>
#include <math.h>

// Problem dims
#define TSTEPS 512
#define BSZ    64
#define INDIM  256
#define HDIM   1024
#define G4     4096
#define N0TOT  5120   // 4096 gate cols + 1024 proj cols
#define K0TOT  1280   // 256 (x) + 1024 (h0)
#define K1TOT  2048   // 1024 (h0') + 1024 (h1)
#define LN_EPS 1e-5f

#define NBLK   256
#define NTHR   1024

// LDS: W1 strip [16 cols][2056] hi then lo (pad 8)
#define LDS_LDK    2056
#define LDS_LO_OFF (16 * LDS_LDK)
#define LDS_W_BYTES (2 * 16 * LDS_LDK * 2)      // 131,584
#define LDS_BYTES  (LDS_W_BYTES + 256)          // + reduce scratch

typedef short          s8v __attribute__((ext_vector_type(8)));
typedef float          f4v __attribute__((ext_vector_type(4)));
typedef unsigned short u16;

__device__ __forceinline__ u16 f2bf(float f) {
    unsigned u = __float_as_uint(f);
    u += 0x7FFFu + ((u >> 16) & 1u);            // RNE
    return (u16)(u >> 16);
}
__device__ __forceinline__ float bf2f(u16 h) {
    return __uint_as_float(((unsigned)h) << 16);
}
__device__ __forceinline__ float sigm(float x) { return 1.f / (1.f + expf(-x)); }

// ---------------- grid barrier -------------------------------------------
// Round-4 lesson: spinning on an ACQUIRE load at agent scope floods the
// fabric with L2 invalidates (buffer_inv per poll) from every idle block,
// destroying the working blocks' caches (MfmaUtil 0.76%, 284us/step).
// Fix: monotonic counter, RELAXED RMW polls (coherent-point, no invalidate),
// s_sleep backoff, exactly one release fence (arrive) + one acquire fence
// (depart) per barrier.
__device__ __forceinline__ void grid_barrier(int* ctr, int expect_total)
{
    __syncthreads();
    if (threadIdx.x == 0) {
        __builtin_amdgcn_fence(__ATOMIC_RELEASE, "agent");   // write back our L2
        __hip_atomic_fetch_add(ctr, 1, __ATOMIC_RELAXED,
                               __HIP_MEMORY_SCOPE_AGENT);
        while (__hip_atomic_fetch_add(ctr, 0, __ATOMIC_RELAXED,
                                      __HIP_MEMORY_SCOPE_AGENT) < expect_total)
            __builtin_amdgcn_s_sleep(32);                    // ~0.85us backoff
        __builtin_amdgcn_fence(__ATOMIC_ACQUIRE, "agent");   // invalidate stale
    }
    __syncthreads();
}

// ---------------- GEMM0 task: one 16x16 tile, K-split 2 ------------------
__device__ __forceinline__ void taskA(int task, int t, int lane,
    const u16* __restrict__ xhi, const u16* __restrict__ xlo,
    const u16* __restrict__ h0hi, const u16* __restrict__ h0lo,
    const u16* __restrict__ W0thi, const u16* __restrict__ W0tlo,
    float* __restrict__ parts0)
{
    const int ks  = task & 1;
    const int tile = task >> 1;
    const int rt  = tile & 3;
    const int ct  = tile >> 2;
    const int row = lane & 15;
    const int kg  = lane >> 4;
    const int m   = rt * 16 + row;
    const int n   = ct * 16 + row;
    int kbeg = ks * 640, kend = kbeg + 640;
    const int klim = (ct >= 256) ? INDIM : K0TOT;
    if (kend > klim) kend = klim;

    f4v acc = {0.f, 0.f, 0.f, 0.f};
    const u16* wh = W0thi + (size_t)n * K0TOT;
    const u16* wl = W0tlo + (size_t)n * K0TOT;

    for (int kc = kbeg; kc < kend; kc += 32) {
        const int kk = kc + kg * 8;
        const u16 *ah, *al;
        if (kc < INDIM) {
            size_t o = ((size_t)(t * BSZ + m)) * INDIM + kk;
            ah = xhi + o; al = xlo + o;
        } else {
            size_t o = (size_t)m * HDIM + (kk - INDIM);
            ah = h0hi + o; al = h0lo + o;
        }
        s8v Ah = *(const s8v*)ah;
        s8v Al = *(const s8v*)al;
        s8v Bh = *(const s8v*)(wh + kk);
        s8v Bl = *(const s8v*)(wl + kk);
        acc = __builtin_amdgcn_mfma_f32_16x16x32_bf16(Ah, Bh, acc, 0, 0, 0);
        acc = __builtin_amdgcn_mfma_f32_16x16x32_bf16(Ah, Bl, acc, 0, 0, 0);
        acc = __builtin_amdgcn_mfma_f32_16x16x32_bf16(Al, Bh, acc, 0, 0, 0);
    }
    float* Cp = parts0 + (size_t)ks * BSZ * N0TOT;
#pragma unroll
    for (int r = 0; r < 4; ++r)
        Cp[(size_t)(rt * 16 + kg * 4 + r) * N0TOT + ct * 16 + row] = acc[r];
}

// ---------------- GEMM1 task: block owns 16 cols (LDS strip) --------------
__device__ __forceinline__ void taskC(int blk, int wv, int lane,
    const u16* __restrict__ shW,
    const u16* __restrict__ h0hi, const u16* __restrict__ h0lo,
    const u16* __restrict__ h1hi, const u16* __restrict__ h1lo,
    float* __restrict__ parts1)
{
    const int rt  = wv & 3;
    const int ks  = wv >> 2;
    const int row = lane & 15;
    const int kg  = lane >> 4;
    const int m   = rt * 16 + row;
    const u16* ahB = (ks < 2) ? h0hi : h1hi;
    const u16* alB = (ks < 2) ? h0lo : h1lo;
    const u16* ah0 = ahB + (size_t)m * HDIM + (ks & 1) * 512;
    const u16* al0 = alB + (size_t)m * HDIM + (ks & 1) * 512;
    const u16* sh  = shW + row * LDS_LDK + ks * 512;
    const u16* sl  = shW + LDS_LO_OFF + row * LDS_LDK + ks * 512;

    f4v acc = {0.f, 0.f, 0.f, 0.f};
#pragma unroll 4
    for (int i = 0; i < 16; ++i) {
        const int kloc = i * 32 + kg * 8;
        s8v Ah = *(const s8v*)(ah0 + kloc);
        s8v Al = *(const s8v*)(al0 + kloc);
        s8v Bh = *(const s8v*)(sh + kloc);
        s8v Bl = *(const s8v*)(sl + kloc);
        acc = __builtin_amdgcn_mfma_f32_16x16x32_bf16(Ah, Bh, acc, 0, 0, 0);
        acc = __builtin_amdgcn_mfma_f32_16x16x32_bf16(Ah, Bl, acc, 0, 0, 0);
        acc = __builtin_amdgcn_mfma_f32_16x16x32_bf16(Al, Bh, acc, 0, 0, 0);
    }
    float* Cp = parts1 + (size_t)ks * BSZ * G4;
#pragma unroll
    for (int r = 0; r < 4; ++r)
        Cp[(size_t)(rt * 16 + kg * 4 + r) * G4 + blk * 16 + row] = acc[r];
}

// ---------------- block-wide sum of (s, q) over 1024 threads --------------
__device__ __forceinline__ float2 blk_sum2(float s, float q, float* red, int tid)
{
#pragma unroll
    for (int off = 32; off; off >>= 1) {
        s += __shfl_down(s, off);
        q += __shfl_down(q, off);
    }
    if ((tid & 63) == 0) { red[(tid >> 6) * 2] = s; red[(tid >> 6) * 2 + 1] = q; }
    __syncthreads();
    float ts = 0.f, tq = 0.f;
#pragma unroll
    for (int i = 0; i < 16; ++i) { ts += red[2 * i]; tq += red[2 * i + 1]; }
    __syncthreads();
    return make_float2(ts, tq);
}

__device__ __forceinline__ float lnorm(float v, float2 sq, float g, float b)
{
    float mean = sq.x * (1.f / 1024.f);
    float var  = sq.y * (1.f / 1024.f) - mean * mean;
    return (v - mean) * rsqrtf(var + LN_EPS) * g + b;
}

// =====================================================================
__global__ __launch_bounds__(NTHR, 4) void persistent(
    const u16* __restrict__ xhi,  const u16* __restrict__ xlo,
    const u16* __restrict__ W0thi, const u16* __restrict__ W0tlo,
    const u16* __restrict__ W1ghi, const u16* __restrict__ W1glo,
    const float* __restrict__ b0, const float* __restrict__ b1,
    const float* __restrict__ lncg, const float* __restrict__ lncb,
    const float* __restrict__ lnhg, const float* __restrict__ lnhb,
    const float* __restrict__ lnog, const float* __restrict__ lnob,
    float* __restrict__ parts0, float* __restrict__ parts1,
    float* __restrict__ h0f, float* __restrict__ c0f,
    float* __restrict__ h1f, float* __restrict__ c1f,
    u16* __restrict__ h0hi, u16* __restrict__ h0lo,
    u16* __restrict__ h1hi, u16* __restrict__ h1lo,
    float* __restrict__ out, int* bar)
{
    extern __shared__ char smem[];
    u16*   shW = (u16*)smem;
    float* red = (float*)(smem + LDS_W_BYTES);

    const int blk  = blockIdx.x;
    const int tid  = threadIdx.x;
    const int wv   = tid >> 6;
    const int lane = tid & 63;
    int nbar = 0;

    // ---- prologue: LDS W1 strip (block owns cols blk*16..+16) ----
    {
        const size_t gcol = (size_t)(blk * 16 + wv) * K1TOT;
        for (int j = lane * 8; j < K1TOT; j += 512) {
            *(s8v*)(shW + wv * LDS_LDK + j)              = *(const s8v*)(W1ghi + gcol + j);
            *(s8v*)(shW + LDS_LO_OFF + wv * LDS_LDK + j) = *(const s8v*)(W1glo + gcol + j);
        }
    }
    // ---- zero states ----
    {
        int gid = blk * NTHR + tid;
        int a = gid >> 16, i = gid & 65535;
        float* dst = (a == 0) ? h0f : (a == 1) ? c0f : (a == 2) ? h1f : c1f;
        dst[i] = 0.f;
        if (a == 0) { h0hi[i] = 0; h0lo[i] = 0; h1hi[i] = 0; h1lo[i] = 0; }
    }
    grid_barrier(bar, (++nbar) * NBLK);

    // ---- A(0) ----
    if (blk >= 64) {
        int wid = (blk - 64) * 16 + wv;
        if (wid < 2560)
            taskA(wid, 0, lane, xhi, xlo, h0hi, h0lo, W0thi, W0tlo, parts0);
    }
    grid_barrier(bar, (++nbar) * NBLK);

    for (int t = 0; t < TSTEPS; ++t) {
        // ---- phase B: cell0 (blocks 0..63, row b = blk) ----
        if (blk < 64) {
            const int b = blk, n = tid;
            const float* P0 = parts0 + (size_t)b * N0TOT;
            const float* P1 = parts0 + (size_t)(BSZ + b) * N0TOT;
            float gi = P0[n]        + P1[n]        + b0[n];
            float gf = P0[1024 + n] + P1[1024 + n] + b0[1024 + n];
            float gg = P0[2048 + n] + P1[2048 + n] + b0[2048 + n];
            float go = P0[3072 + n] + P1[3072 + n] + b0[3072 + n];
            float xp = P0[4096 + n] + P1[4096 + n];
            float cv = sigm(gf) * c0f[b * HDIM + n] + expf(gi) * tanhf(gg);
            float2 r = blk_sum2(cv, cv * cv, red, tid);
            float cl = lnorm(cv, r, lncg[n], lncb[n]);
            c0f[b * HDIM + n] = cl;
            float hv = sigm(go) * tanhf(cl);
            r = blk_sum2(hv, hv * hv, red, tid);
            float hl = lnorm(hv, r, lnhg[n], lnhb[n]) + xp;
            r = blk_sum2(hl, hl * hl, red, tid);
            float hn = lnorm(hl, r, lnog[n], lnob[n]);
            h0f[b * HDIM + n] = hn;
            u16 hi = f2bf(hn);
            h0hi[b * HDIM + n] = hi;
            h0lo[b * HDIM + n] = f2bf(hn - bf2f(hi));
        }
        grid_barrier(bar, (++nbar) * NBLK);

        // ---- phase C: GEMM1 (all blocks, own 16-col LDS strip) ----
        taskC(blk, wv, lane, shW, h0hi, h0lo, h1hi, h1lo, parts1);
        grid_barrier(bar, (++nbar) * NBLK);

        // ---- phase D (cell1, blocks 0..63) || A(t+1) (blocks 64..255) ----
        if (blk < 64) {
            const int b = blk, n = tid;
            const float* P0 = parts1 + (size_t)b * G4;
            const float* P1 = parts1 + (size_t)(64 + b) * G4;
            const float* P2 = parts1 + (size_t)(128 + b) * G4;
            const float* P3 = parts1 + (size_t)(192 + b) * G4;
            float gi = P0[n] + P1[n] + P2[n] + P3[n] + b1[n];
            float gf = P0[1024 + n] + P1[1024 + n] + P2[1024 + n] + P3[1024 + n] + b1[1024 + n];
            float gg = P0[2048 + n] + P1[2048 + n] + P2[2048 + n] + P3[2048 + n] + b1[2048 + n];
            float go = P0[3072 + n] + P1[3072 + n] + P2[3072 + n] + P3[3072 + n] + b1[3072 + n];
            float cv = sigm(gf) * c1f[b * HDIM + n] + expf(gi) * tanhf(gg);
            float2 r = blk_sum2(cv, cv * cv, red, tid);
            float cl = lnorm(cv, r, lncg[HDIM + n], lncb[HDIM + n]);
            c1f[b * HDIM + n] = cl;
            float hv = sigm(go) * tanhf(cl);
            r = blk_sum2(hv, hv * hv, red, tid);
            float hl = lnorm(hv, r, lnhg[HDIM + n], lnhb[HDIM + n]) + h0f[b * HDIM + n];
            r = blk_sum2(hl, hl * hl, red, tid);
            float hn = lnorm(hl, r, lnog[HDIM + n], lnob[HDIM + n]);
            h1f[b * HDIM + n] = hn;
            u16 hi = f2bf(hn);
            h1hi[b * HDIM + n] = hi;
            h1lo[b * HDIM + n] = f2bf(hn - bf2f(hi));
            out[(size_t)t * BSZ * HDIM + b * HDIM + n] = hn;
        } else if (t + 1 < TSTEPS) {
            int wid = (blk - 64) * 16 + wv;
            if (wid < 2560)
                taskA(wid, t + 1, lane, xhi, xlo, h0hi, h0lo, W0thi, W0tlo, parts0);
        }
        grid_barrier(bar, (++nbar) * NBLK);
    }

    // ---- final states: h0,h1 then c0,c1 ----
    {
        int gid = blk * NTHR + tid;
        int a = gid >> 16, i = gid & 65535;
        const float* src = (a == 0) ? h0f : (a == 1) ? h1f : (a == 2) ? c0f : c1f;
        out[(size_t)TSTEPS * BSZ * HDIM + (size_t)a * 65536 + i] = src[i];
    }
}

// =====================================================================
// prep kernels
// =====================================================================
__global__ __launch_bounds__(256) void transpose_split(
    const float* __restrict__ src, int N,
    u16* __restrict__ dsthi, u16* __restrict__ dstlo,
    int ldd, int noff, int koff)
{
    __shared__ float tile[32][33];
    const int n0 = blockIdx.x * 32, k0 = blockIdx.y * 32;
    const int tx = threadIdx.x & 31, ty = threadIdx.x >> 5;
#pragma unroll
    for (int i = 0; i < 4; ++i)
        tile[ty + i * 8][tx] = src[(size_t)(k0 + ty + i * 8) * N + n0 + tx];
    __syncthreads();
#pragma unroll
    for (int i = 0; i < 4; ++i) {
        float v = tile[tx][ty + i * 8];
        u16 hi = f2bf(v);
        u16 lo = f2bf(v - bf2f(hi));
        size_t idx = (size_t)(n0 + ty + i * 8 + noff) * ldd + k0 + koff + tx;
        dsthi[idx] = hi;
        dstlo[idx] = lo;
    }
}

__global__ void conv_split(const float* __restrict__ src,
                           u16* __restrict__ hi, u16* __restrict__ lo, int n4)
{
    int i = blockIdx.x * 256 + threadIdx.x;
    if (i < n4) {
        float4 v = ((const float4*)src)[i];
        ushort4 h, l;
        h.x = f2bf(v.x); l.x = f2bf(v.x - bf2f(h.x));
        h.y = f2bf(v.y); l.y = f2bf(v.y - bf2f(h.y));
        h.z = f2bf(v.z); l.z = f2bf(v.z - bf2f(h.z));
        h.w = f2bf(v.w); l.w = f2bf(v.w - bf2f(h.w));
        ((ushort4*)hi)[i] = h;
        ((ushort4*)lo)[i] = l;
    }
}

// =====================================================================
extern "C" void kernel_launch(void* const* d_in, const int* in_sizes, int n_in,
                              void* d_out, int out_size, void* d_ws, size_t ws_size,
                              hipStream_t stream)
{
    const float* x     = (const float*)d_in[0];
    const float* Wproj = (const float*)d_in[1];
    const float* Wx0   = (const float*)d_in[2];
    const float* Wh0   = (const float*)d_in[3];
    const float* b0    = (const float*)d_in[4];
    const float* Wx1   = (const float*)d_in[5];
    const float* Wh1   = (const float*)d_in[6];
    const float* b1    = (const float*)d_in[7];
    const float* lnc_g = (const float*)d_in[8];
    const float* lnc_b = (const float*)d_in[9];
    const float* lnh_g = (const float*)d_in[10];
    const float* lnh_b = (const float*)d_in[11];
    const float* lno_g = (const float*)d_in[12];
    const float* lno_b = (const float*)d_in[13];
    float* out = (float*)d_out;

    // ---- ws layout ----
    char* base = (char*)d_ws;
    size_t o = 0;
    u16* x_hi  = (u16*)(base + o); o += (size_t)TSTEPS * BSZ * INDIM * 2;
    u16* x_lo  = (u16*)(base + o); o += (size_t)TSTEPS * BSZ * INDIM * 2;
    u16* W0thi = (u16*)(base + o); o += (size_t)N0TOT * K0TOT * 2;
    u16* W0tlo = (u16*)(base + o); o += (size_t)N0TOT * K0TOT * 2;
    u16* W1ghi = (u16*)(base + o); o += (size_t)G4 * K1TOT * 2;
    u16* W1glo = (u16*)(base + o); o += (size_t)G4 * K1TOT * 2;
    float* parts0 = (float*)(base + o); o += (size_t)2 * BSZ * N0TOT * 4;
    float* parts1 = (float*)(base + o); o += (size_t)4 * BSZ * G4 * 4;
    float* h0f = (float*)(base + o); o += 65536 * 4;
    float* c0f = (float*)(base + o); o += 65536 * 4;
    float* h1f = (float*)(base + o); o += 65536 * 4;
    float* c1f = (float*)(base + o); o += 65536 * 4;
    u16* h0hi = (u16*)(base + o); o += 65536 * 2;
    u16* h0lo = (u16*)(base + o); o += 65536 * 2;
    u16* h1hi = (u16*)(base + o); o += 65536 * 2;
    u16* h1lo = (u16*)(base + o); o += 65536 * 2;
    int* bar  = (int*)(base + o); o += 256;
    if (ws_size < o) return;

    // ---- prep ----
    conv_split<<<dim3(8192), 256, 0, stream>>>(x, x_hi, x_lo, 2097152);
    hipMemsetAsync(W0thi, 0, (size_t)2 * N0TOT * K0TOT * 2, stream);
    transpose_split<<<dim3(128, 8),  256, 0, stream>>>(Wx0,   G4,   W0thi, W0tlo, K0TOT, 0,    0);
    transpose_split<<<dim3(128, 32), 256, 0, stream>>>(Wh0,   G4,   W0thi, W0tlo, K0TOT, 0,    256);
    transpose_split<<<dim3(32, 8),   256, 0, stream>>>(Wproj, HDIM, W0thi, W0tlo, K0TOT, 4096, 0);
    transpose_split<<<dim3(128, 32), 256, 0, stream>>>(Wx1,   G4,   W1ghi, W1glo, K1TOT, 0,    0);
    transpose_split<<<dim3(128, 32), 256, 0, stream>>>(Wh1,   G4,   W1ghi, W1glo, K1TOT, 0,    1024);
    hipMemsetAsync(bar, 0, 256, stream);

    // ---- the whole recurrence: one persistent kernel ----
    persistent<<<dim3(NBLK), dim3(NTHR), LDS_BYTES, stream>>>(
        x_hi, x_lo, W0thi, W0tlo, W1ghi, W1glo, b0, b1,
        lnc_g, lnc_b, lnh_g, lnh_b, lno_g, lno_b,
        parts0, parts1, h0f, c0f, h1f, c1f,
        h0hi, h0lo, h1hi, h1lo, out, bar);
}

// Round 6
// 52089.093 us; speedup vs baseline: 2.7978x; 1.0409x over previous
//
#include <hip/hip_runtime.h>
#include <math.h>

// Problem dims
#define TSTEPS 512
#define BSZ    64
#define INDIM  256
#define HDIM   1024
#define G4     4096
#define N0TOT  5120   // 4096 gate cols + 1024 proj cols
#define K0TOT  1280   // 256 (x) + 1024 (h0)
#define K1TOT  2048   // 1024 (h0') + 1024 (h1)
#define LN_EPS 1e-5f

#define NBLK   256
#define NTHR   1024

// LDS: W1 strip [16 cols][2056] hi then lo (pad 8)
#define LDS_LDK    2056
#define LDS_LO_OFF (16 * LDS_LDK)
#define LDS_W_BYTES (2 * 16 * LDS_LDK * 2)      // 131,584
#define LDS_BYTES  (LDS_W_BYTES + 256)          // + reduce scratch

typedef short          s8v __attribute__((ext_vector_type(8)));
typedef float          f4v __attribute__((ext_vector_type(4)));
typedef unsigned short u16;

__device__ __forceinline__ u16 f2bf(float f) {
    unsigned u = __float_as_uint(f);
    u += 0x7FFFu + ((u >> 16) & 1u);            // RNE
    return (u16)(u >> 16);
}
__device__ __forceinline__ float bf2f(u16 h) {
    return __uint_as_float(((unsigned)h) << 16);
}
__device__ __forceinline__ float sigm(float x) { return 1.f / (1.f + expf(-x)); }

// ---------------- grid barrier -------------------------------------------
// R4 lesson: ACQUIRE-load tight-spin -> buffer_inv per poll -> cache death.
// R5 lesson: RMW (fetch_add 0) polls serialize on one cacheline at the
//            coherent point -> ~30us/barrier queueing.
// R6: arrive with one RMW; poll with RELAXED agent-scope atomic LOAD
// (L2-bypass on gfx950 multi-XCD -> reads L3 directly; concurrent,
// non-invalidating, non-serializing) + s_sleep(8) backoff. Every 64th poll
// falls back to the RMW form as a guaranteed-progress safety net. One
// release fence at arrive, one acquire fence at depart.
__device__ __forceinline__ void grid_barrier(int* ctr, int expect_total)
{
    __syncthreads();
    if (threadIdx.x == 0) {
        __builtin_amdgcn_fence(__ATOMIC_RELEASE, "agent");   // wb our L2
        __hip_atomic_fetch_add(ctr, 1, __ATOMIC_RELAXED,
                               __HIP_MEMORY_SCOPE_AGENT);
        int spins = 0;
        for (;;) {
            int v = (++spins & 63)
                ? __hip_atomic_load(ctr, __ATOMIC_RELAXED,
                                    __HIP_MEMORY_SCOPE_AGENT)
                : __hip_atomic_fetch_add(ctr, 0, __ATOMIC_RELAXED,
                                         __HIP_MEMORY_SCOPE_AGENT);
            if (v >= expect_total) break;
            __builtin_amdgcn_s_sleep(8);                     // ~0.2us backoff
        }
        __builtin_amdgcn_fence(__ATOMIC_ACQUIRE, "agent");   // inv stale L2
    }
    __syncthreads();
}

// ---------------- GEMM0 task: one 16x16 tile, K-split 2 ------------------
__device__ __forceinline__ void taskA(int task, int t, int lane,
    const u16* __restrict__ xhi, const u16* __restrict__ xlo,
    const u16* __restrict__ h0hi, const u16* __restrict__ h0lo,
    const u16* __restrict__ W0thi, const u16* __restrict__ W0tlo,
    float* __restrict__ parts0)
{
    const int ks  = task & 1;
    const int tile = task >> 1;
    const int rt  = tile & 3;
    const int ct  = tile >> 2;
    const int row = lane & 15;
    const int kg  = lane >> 4;
    const int m   = rt * 16 + row;
    const int n   = ct * 16 + row;
    int kbeg = ks * 640, kend = kbeg + 640;
    const int klim = (ct >= 256) ? INDIM : K0TOT;
    if (kend > klim) kend = klim;

    f4v acc = {0.f, 0.f, 0.f, 0.f};
    const u16* wh = W0thi + (size_t)n * K0TOT;
    const u16* wl = W0tlo + (size_t)n * K0TOT;

    for (int kc = kbeg; kc < kend; kc += 32) {
        const int kk = kc + kg * 8;
        const u16 *ah, *al;
        if (kc < INDIM) {
            size_t o = ((size_t)(t * BSZ + m)) * INDIM + kk;
            ah = xhi + o; al = xlo + o;
        } else {
            size_t o = (size_t)m * HDIM + (kk - INDIM);
            ah = h0hi + o; al = h0lo + o;
        }
        s8v Ah = *(const s8v*)ah;
        s8v Al = *(const s8v*)al;
        s8v Bh = *(const s8v*)(wh + kk);
        s8v Bl = *(const s8v*)(wl + kk);
        acc = __builtin_amdgcn_mfma_f32_16x16x32_bf16(Ah, Bh, acc, 0, 0, 0);
        acc = __builtin_amdgcn_mfma_f32_16x16x32_bf16(Ah, Bl, acc, 0, 0, 0);
        acc = __builtin_amdgcn_mfma_f32_16x16x32_bf16(Al, Bh, acc, 0, 0, 0);
    }
    float* Cp = parts0 + (size_t)ks * BSZ * N0TOT;
#pragma unroll
    for (int r = 0; r < 4; ++r)
        Cp[(size_t)(rt * 16 + kg * 4 + r) * N0TOT + ct * 16 + row] = acc[r];
}

// ---------------- GEMM1 task: block owns 16 cols (LDS strip) --------------
__device__ __forceinline__ void taskC(int blk, int wv, int lane,
    const u16* __restrict__ shW,
    const u16* __restrict__ h0hi, const u16* __restrict__ h0lo,
    const u16* __restrict__ h1hi, const u16* __restrict__ h1lo,
    float* __restrict__ parts1)
{
    const int rt  = wv & 3;
    const int ks  = wv >> 2;
    const int row = lane & 15;
    const int kg  = lane >> 4;
    const int m   = rt * 16 + row;
    const u16* ahB = (ks < 2) ? h0hi : h1hi;
    const u16* alB = (ks < 2) ? h0lo : h1lo;
    const u16* ah0 = ahB + (size_t)m * HDIM + (ks & 1) * 512;
    const u16* al0 = alB + (size_t)m * HDIM + (ks & 1) * 512;
    const u16* sh  = shW + row * LDS_LDK + ks * 512;
    const u16* sl  = shW + LDS_LO_OFF + row * LDS_LDK + ks * 512;

    f4v acc = {0.f, 0.f, 0.f, 0.f};
#pragma unroll 4
    for (int i = 0; i < 16; ++i) {
        const int kloc = i * 32 + kg * 8;
        s8v Ah = *(const s8v*)(ah0 + kloc);
        s8v Al = *(const s8v*)(al0 + kloc);
        s8v Bh = *(const s8v*)(sh + kloc);
        s8v Bl = *(const s8v*)(sl + kloc);
        acc = __builtin_amdgcn_mfma_f32_16x16x32_bf16(Ah, Bh, acc, 0, 0, 0);
        acc = __builtin_amdgcn_mfma_f32_16x16x32_bf16(Ah, Bl, acc, 0, 0, 0);
        acc = __builtin_amdgcn_mfma_f32_16x16x32_bf16(Al, Bh, acc, 0, 0, 0);
    }
    float* Cp = parts1 + (size_t)ks * BSZ * G4;
#pragma unroll
    for (int r = 0; r < 4; ++r)
        Cp[(size_t)(rt * 16 + kg * 4 + r) * G4 + blk * 16 + row] = acc[r];
}

// ---------------- block-wide sum of (s, q) over 1024 threads --------------
__device__ __forceinline__ float2 blk_sum2(float s, float q, float* red, int tid)
{
#pragma unroll
    for (int off = 32; off; off >>= 1) {
        s += __shfl_down(s, off);
        q += __shfl_down(q, off);
    }
    if ((tid & 63) == 0) { red[(tid >> 6) * 2] = s; red[(tid >> 6) * 2 + 1] = q; }
    __syncthreads();
    float ts = 0.f, tq = 0.f;
#pragma unroll
    for (int i = 0; i < 16; ++i) { ts += red[2 * i]; tq += red[2 * i + 1]; }
    __syncthreads();
    return make_float2(ts, tq);
}

__device__ __forceinline__ float lnorm(float v, float2 sq, float g, float b)
{
    float mean = sq.x * (1.f / 1024.f);
    float var  = sq.y * (1.f / 1024.f) - mean * mean;
    return (v - mean) * rsqrtf(var + LN_EPS) * g + b;
}

// =====================================================================
__global__ __launch_bounds__(NTHR, 4) void persistent(
    const u16* __restrict__ xhi,  const u16* __restrict__ xlo,
    const u16* __restrict__ W0thi, const u16* __restrict__ W0tlo,
    const u16* __restrict__ W1ghi, const u16* __restrict__ W1glo,
    const float* __restrict__ b0, const float* __restrict__ b1,
    const float* __restrict__ lncg, const float* __restrict__ lncb,
    const float* __restrict__ lnhg, const float* __restrict__ lnhb,
    const float* __restrict__ lnog, const float* __restrict__ lnob,
    float* __restrict__ parts0, float* __restrict__ parts1,
    float* __restrict__ h0f, float* __restrict__ c0f,
    float* __restrict__ h1f, float* __restrict__ c1f,
    u16* __restrict__ h0hi, u16* __restrict__ h0lo,
    u16* __restrict__ h1hi, u16* __restrict__ h1lo,
    float* __restrict__ out, int* bar)
{
    extern __shared__ char smem[];
    u16*   shW = (u16*)smem;
    float* red = (float*)(smem + LDS_W_BYTES);

    const int blk  = blockIdx.x;
    const int tid  = threadIdx.x;
    const int wv   = tid >> 6;
    const int lane = tid & 63;
    int nbar = 0;

    // ---- prologue: LDS W1 strip (block owns cols blk*16..+16) ----
    {
        const size_t gcol = (size_t)(blk * 16 + wv) * K1TOT;
        for (int j = lane * 8; j < K1TOT; j += 512) {
            *(s8v*)(shW + wv * LDS_LDK + j)              = *(const s8v*)(W1ghi + gcol + j);
            *(s8v*)(shW + LDS_LO_OFF + wv * LDS_LDK + j) = *(const s8v*)(W1glo + gcol + j);
        }
    }
    // ---- zero states ----
    {
        int gid = blk * NTHR + tid;
        int a = gid >> 16, i = gid & 65535;
        float* dst = (a == 0) ? h0f : (a == 1) ? c0f : (a == 2) ? h1f : c1f;
        dst[i] = 0.f;
        if (a == 0) { h0hi[i] = 0; h0lo[i] = 0; h1hi[i] = 0; h1lo[i] = 0; }
    }
    grid_barrier(bar, (++nbar) * NBLK);

    // ---- A(0) ----
    if (blk >= 64) {
        int wid = (blk - 64) * 16 + wv;
        if (wid < 2560)
            taskA(wid, 0, lane, xhi, xlo, h0hi, h0lo, W0thi, W0tlo, parts0);
    }
    grid_barrier(bar, (++nbar) * NBLK);

    for (int t = 0; t < TSTEPS; ++t) {
        // ---- phase B: cell0 (blocks 0..63, row b = blk) ----
        if (blk < 64) {
            const int b = blk, n = tid;
            const float* P0 = parts0 + (size_t)b * N0TOT;
            const float* P1 = parts0 + (size_t)(BSZ + b) * N0TOT;
            float gi = P0[n]        + P1[n]        + b0[n];
            float gf = P0[1024 + n] + P1[1024 + n] + b0[1024 + n];
            float gg = P0[2048 + n] + P1[2048 + n] + b0[2048 + n];
            float go = P0[3072 + n] + P1[3072 + n] + b0[3072 + n];
            float xp = P0[4096 + n] + P1[4096 + n];
            float cv = sigm(gf) * c0f[b * HDIM + n] + expf(gi) * tanhf(gg);
            float2 r = blk_sum2(cv, cv * cv, red, tid);
            float cl = lnorm(cv, r, lncg[n], lncb[n]);
            c0f[b * HDIM + n] = cl;
            float hv = sigm(go) * tanhf(cl);
            r = blk_sum2(hv, hv * hv, red, tid);
            float hl = lnorm(hv, r, lnhg[n], lnhb[n]) + xp;
            r = blk_sum2(hl, hl * hl, red, tid);
            float hn = lnorm(hl, r, lnog[n], lnob[n]);
            h0f[b * HDIM + n] = hn;
            u16 hi = f2bf(hn);
            h0hi[b * HDIM + n] = hi;
            h0lo[b * HDIM + n] = f2bf(hn - bf2f(hi));
        }
        grid_barrier(bar, (++nbar) * NBLK);

        // ---- phase C: GEMM1 (all blocks, own 16-col LDS strip) ----
        taskC(blk, wv, lane, shW, h0hi, h0lo, h1hi, h1lo, parts1);
        grid_barrier(bar, (++nbar) * NBLK);

        // ---- phase D (cell1, blocks 0..63) || A(t+1) (blocks 64..255) ----
        if (blk < 64) {
            const int b = blk, n = tid;
            const float* P0 = parts1 + (size_t)b * G4;
            const float* P1 = parts1 + (size_t)(64 + b) * G4;
            const float* P2 = parts1 + (size_t)(128 + b) * G4;
            const float* P3 = parts1 + (size_t)(192 + b) * G4;
            float gi = P0[n] + P1[n] + P2[n] + P3[n] + b1[n];
            float gf = P0[1024 + n] + P1[1024 + n] + P2[1024 + n] + P3[1024 + n] + b1[1024 + n];
            float gg = P0[2048 + n] + P1[2048 + n] + P2[2048 + n] + P3[2048 + n] + b1[2048 + n];
            float go = P0[3072 + n] + P1[3072 + n] + P2[3072 + n] + P3[3072 + n] + b1[3072 + n];
            float cv = sigm(gf) * c1f[b * HDIM + n] + expf(gi) * tanhf(gg);
            float2 r = blk_sum2(cv, cv * cv, red, tid);
            float cl = lnorm(cv, r, lncg[HDIM + n], lncb[HDIM + n]);
            c1f[b * HDIM + n] = cl;
            float hv = sigm(go) * tanhf(cl);
            r = blk_sum2(hv, hv * hv, red, tid);
            float hl = lnorm(hv, r, lnhg[HDIM + n], lnhb[HDIM + n]) + h0f[b * HDIM + n];
            r = blk_sum2(hl, hl * hl, red, tid);
            float hn = lnorm(hl, r, lnog[HDIM + n], lnob[HDIM + n]);
            h1f[b * HDIM + n] = hn;
            u16 hi = f2bf(hn);
            h1hi[b * HDIM + n] = hi;
            h1lo[b * HDIM + n] = f2bf(hn - bf2f(hi));
            out[(size_t)t * BSZ * HDIM + b * HDIM + n] = hn;
        } else if (t + 1 < TSTEPS) {
            int wid = (blk - 64) * 16 + wv;
            if (wid < 2560)
                taskA(wid, t + 1, lane, xhi, xlo, h0hi, h0lo, W0thi, W0tlo, parts0);
        }
        grid_barrier(bar, (++nbar) * NBLK);
    }

    // ---- final states: h0,h1 then c0,c1 ----
    {
        int gid = blk * NTHR + tid;
        int a = gid >> 16, i = gid & 65535;
        const float* src = (a == 0) ? h0f : (a == 1) ? h1f : (a == 2) ? c0f : c1f;
        out[(size_t)TSTEPS * BSZ * HDIM + (size_t)a * 65536 + i] = src[i];
    }
}

// =====================================================================
// prep kernels
// =====================================================================
__global__ __launch_bounds__(256) void transpose_split(
    const float* __restrict__ src, int N,
    u16* __restrict__ dsthi, u16* __restrict__ dstlo,
    int ldd, int noff, int koff)
{
    __shared__ float tile[32][33];
    const int n0 = blockIdx.x * 32, k0 = blockIdx.y * 32;
    const int tx = threadIdx.x & 31, ty = threadIdx.x >> 5;
#pragma unroll
    for (int i = 0; i < 4; ++i)
        tile[ty + i * 8][tx] = src[(size_t)(k0 + ty + i * 8) * N + n0 + tx];
    __syncthreads();
#pragma unroll
    for (int i = 0; i < 4; ++i) {
        float v = tile[tx][ty + i * 8];
        u16 hi = f2bf(v);
        u16 lo = f2bf(v - bf2f(hi));
        size_t idx = (size_t)(n0 + ty + i * 8 + noff) * ldd + k0 + koff + tx;
        dsthi[idx] = hi;
        dstlo[idx] = lo;
    }
}

__global__ void conv_split(const float* __restrict__ src,
                           u16* __restrict__ hi, u16* __restrict__ lo, int n4)
{
    int i = blockIdx.x * 256 + threadIdx.x;
    if (i < n4) {
        float4 v = ((const float4*)src)[i];
        ushort4 h, l;
        h.x = f2bf(v.x); l.x = f2bf(v.x - bf2f(h.x));
        h.y = f2bf(v.y); l.y = f2bf(v.y - bf2f(h.y));
        h.z = f2bf(v.z); l.z = f2bf(v.z - bf2f(h.z));
        h.w = f2bf(v.w); l.w = f2bf(v.w - bf2f(h.w));
        ((ushort4*)hi)[i] = h;
        ((ushort4*)lo)[i] = l;
    }
}

// =====================================================================
extern "C" void kernel_launch(void* const* d_in, const int* in_sizes, int n_in,
                              void* d_out, int out_size, void* d_ws, size_t ws_size,
                              hipStream_t stream)
{
    const float* x     = (const float*)d_in[0];
    const float* Wproj = (const float*)d_in[1];
    const float* Wx0   = (const float*)d_in[2];
    const float* Wh0   = (const float*)d_in[3];
    const float* b0    = (const float*)d_in[4];
    const float* Wx1   = (const float*)d_in[5];
    const float* Wh1   = (const float*)d_in[6];
    const float* b1    = (const float*)d_in[7];
    const float* lnc_g = (const float*)d_in[8];
    const float* lnc_b = (const float*)d_in[9];
    const float* lnh_g = (const float*)d_in[10];
    const float* lnh_b = (const float*)d_in[11];
    const float* lno_g = (const float*)d_in[12];
    const float* lno_b = (const float*)d_in[13];
    float* out = (float*)d_out;

    // ---- ws layout ----
    char* base = (char*)d_ws;
    size_t o = 0;
    u16* x_hi  = (u16*)(base + o); o += (size_t)TSTEPS * BSZ * INDIM * 2;
    u16* x_lo  = (u16*)(base + o); o += (size_t)TSTEPS * BSZ * INDIM * 2;
    u16* W0thi = (u16*)(base + o); o += (size_t)N0TOT * K0TOT * 2;
    u16* W0tlo = (u16*)(base + o); o += (size_t)N0TOT * K0TOT * 2;
    u16* W1ghi = (u16*)(base + o); o += (size_t)G4 * K1TOT * 2;
    u16* W1glo = (u16*)(base + o); o += (size_t)G4 * K1TOT * 2;
    float* parts0 = (float*)(base + o); o += (size_t)2 * BSZ * N0TOT * 4;
    float* parts1 = (float*)(base + o); o += (size_t)4 * BSZ * G4 * 4;
    float* h0f = (float*)(base + o); o += 65536 * 4;
    float* c0f = (float*)(base + o); o += 65536 * 4;
    float* h1f = (float*)(base + o); o += 65536 * 4;
    float* c1f = (float*)(base + o); o += 65536 * 4;
    u16* h0hi = (u16*)(base + o); o += 65536 * 2;
    u16* h0lo = (u16*)(base + o); o += 65536 * 2;
    u16* h1hi = (u16*)(base + o); o += 65536 * 2;
    u16* h1lo = (u16*)(base + o); o += 65536 * 2;
    int* bar  = (int*)(base + o); o += 256;
    if (ws_size < o) return;

    // ---- prep ----
    conv_split<<<dim3(8192), 256, 0, stream>>>(x, x_hi, x_lo, 2097152);
    hipMemsetAsync(W0thi, 0, (size_t)2 * N0TOT * K0TOT * 2, stream);
    transpose_split<<<dim3(128, 8),  256, 0, stream>>>(Wx0,   G4,   W0thi, W0tlo, K0TOT, 0,    0);
    transpose_split<<<dim3(128, 32), 256, 0, stream>>>(Wh0,   G4,   W0thi, W0tlo, K0TOT, 0,    256);
    transpose_split<<<dim3(32, 8),   256, 0, stream>>>(Wproj, HDIM, W0thi, W0tlo, K0TOT, 4096, 0);
    transpose_split<<<dim3(128, 32), 256, 0, stream>>>(Wx1,   G4,   W1ghi, W1glo, K1TOT, 0,    0);
    transpose_split<<<dim3(128, 32), 256, 0, stream>>>(Wh1,   G4,   W1ghi, W1glo, K1TOT, 0,    1024);
    hipMemsetAsync(bar, 0, 256, stream);

    // ---- the whole recurrence: one persistent kernel ----
    persistent<<<dim3(NBLK), dim3(NTHR), LDS_BYTES, stream>>>(
        x_hi, x_lo, W0thi, W0tlo, W1ghi, W1glo, b0, b1,
        lnc_g, lnc_b, lnh_g, lnh_b, lno_g, lno_b,
        parts0, parts1, h0f, c0f, h1f, c1f,
        h0hi, h0lo, h1hi, h1lo, out, bar);
}